// Round 1
// baseline (139.451 us; speedup 1.0000x reference)
//
#include <hip/hip_runtime.h>

// Problem constants (fixed by setup_inputs)
#define BB 4
#define SS 2048
#define HH 4096
#define KVH 8
#define DD 128
#define MAXSEQ 4096
#define RANK 64
#define HDN 1024   // H/4

// Workspace layout (floats):
//   [0, 16384)      pooled sums  (B*H)
//   [16384, 20480)  hdn          (B*HDN)
//   [20480, 20488)  strat        (B*2)  -> w_dense, w_lr per batch
//   ints at float offset 20488: inv[SS]
#define WS_POOLED 0
#define WS_HDN    16384
#define WS_STRAT  20480
#define WS_FLOATS 20488

__global__ void init_ws_kernel(float* __restrict__ wsf, int* __restrict__ inv) {
    int idx = blockIdx.x * 256 + threadIdx.x;
    if (idx < WS_FLOATS) wsf[idx] = 0.0f;
    int j = idx - WS_FLOATS;
    if (j >= 0 && j < SS) inv[j] = -1;
}

__global__ void scatter_inv_kernel(const int* __restrict__ cache_position,
                                   int* __restrict__ inv) {
    int i = blockIdx.x * 256 + threadIdx.x;
    if (i < SS) {
        int pos = cache_position[i];
        if (pos >= 0 && pos < SS) atomicMax(&inv[pos], i);  // last-wins for dupes
    }
}

// pooled[b][c] += sum over a 64-element s-chunk of hidden[b,s,c]
// grid = B * (S/64) * (H/256) = 2048 blocks, 256 threads
__global__ void pool_kernel(const float* __restrict__ hidden,
                            float* __restrict__ pooled) {
    int blk = blockIdx.x;
    int cblk = blk % (HH / 256); blk /= (HH / 256);
    int sch  = blk % (SS / 64);  blk /= (SS / 64);
    int b = blk;
    int c = cblk * 256 + threadIdx.x;
    const float* base = hidden + (size_t)b * SS * HH + (size_t)sch * 64 * HH + c;
    float acc = 0.0f;
    #pragma unroll 8
    for (int s = 0; s < 64; ++s) acc += base[(size_t)s * HH];
    atomicAdd(&pooled[b * HH + c], acc);
}

// hdn[b][j] += sum_k feats[b][k] * w1[k][j] over a 128-row k-chunk
// grid = (HDN/256) * 33 blocks (33*128 = 4224 >= 4098), 256 threads
__global__ void mlp1_kernel(const float* __restrict__ wsf,
                            const float* __restrict__ w1,
                            const int* __restrict__ layer_idx,
                            float* __restrict__ hdn) {
    int jb = blockIdx.x % (HDN / 256);
    int kc = blockIdx.x / (HDN / 256);
    int j = jb * 256 + threadIdx.x;
    const float* pooled = wsf + WS_POOLED;
    const float inv_s = 1.0f / (float)SS;
    float li = (float)(*layer_idx);
    float acc0 = 0.f, acc1 = 0.f, acc2 = 0.f, acc3 = 0.f;
    int k0 = kc * 128;
    for (int kk = 0; kk < 128; ++kk) {
        int k = k0 + kk;
        if (k >= HH + 2) break;
        float w = w1[(size_t)k * HDN + j];
        float f0, f1, f2, f3;
        if (k < HH) {
            f0 = pooled[0 * HH + k] * inv_s;
            f1 = pooled[1 * HH + k] * inv_s;
            f2 = pooled[2 * HH + k] * inv_s;
            f3 = pooled[3 * HH + k] * inv_s;
        } else if (k == HH) { f0 = f1 = f2 = f3 = li; }
        else                { f0 = f1 = f2 = f3 = (float)SS; }
        acc0 = fmaf(f0, w, acc0);
        acc1 = fmaf(f1, w, acc1);
        acc2 = fmaf(f2, w, acc2);
        acc3 = fmaf(f3, w, acc3);
    }
    atomicAdd(&hdn[0 * HDN + j], acc0);
    atomicAdd(&hdn[1 * HDN + j], acc1);
    atomicAdd(&hdn[2 * HDN + j], acc2);
    atomicAdd(&hdn[3 * HDN + j], acc3);
}

// logits = relu(hdn + b1) @ w2 + b2 ; softmax ; write strat[b*2 + {0,1}]
__global__ void mlp2_kernel(const float* __restrict__ hdn,
                            const float* __restrict__ b1,
                            const float* __restrict__ w2,
                            const float* __restrict__ b2,
                            float* __restrict__ strat) {
    __shared__ float red[256];
    __shared__ float logits[BB][4];
    int t = threadIdx.x;
    for (int b = 0; b < BB; ++b) {
        for (int m = 0; m < 4; ++m) {
            float acc = 0.0f;
            for (int j = t; j < HDN; j += 256) {
                float h = hdn[b * HDN + j] + b1[j];
                h = h > 0.0f ? h : 0.0f;
                acc = fmaf(h, w2[j * 4 + m], acc);
            }
            red[t] = acc; __syncthreads();
            for (int off = 128; off > 0; off >>= 1) {
                if (t < off) red[t] += red[t + off];
                __syncthreads();
            }
            if (t == 0) logits[b][m] = red[0] + b2[m];
            __syncthreads();
        }
    }
    if (t == 0) {
        for (int b = 0; b < BB; ++b) {
            float mx = fmaxf(fmaxf(logits[b][0], logits[b][1]),
                             fmaxf(logits[b][2], logits[b][3]));
            float e0 = __expf(logits[b][0] - mx);
            float e1 = __expf(logits[b][1] - mx);
            float e2 = __expf(logits[b][2] - mx);
            float e3 = __expf(logits[b][3] - mx);
            float denom = e0 + e1 + e2 + e3;
            strat[b * 2 + 0] = e0 / denom;
            strat[b * 2 + 1] = e1 / denom;
        }
    }
}

// One thread per float4 of (b,h,s,d): computes BOTH k_out and v_out.
// linear idx = bh*(S*32) + s*32 + d4  ==  output float4 index for k.
__global__ void out_kernel(const float* __restrict__ key,
                           const float* __restrict__ value,
                           const float* __restrict__ k_cache,
                           const float* __restrict__ v_cache,
                           const float* __restrict__ k_left,
                           const float* __restrict__ v_left,
                           const float* __restrict__ strat,
                           const int* __restrict__ inv,
                           float* __restrict__ out) {
    int idx = blockIdx.x * 256 + threadIdx.x;   // < 4,194,304
    int d4 = idx & 31;          // D/4 = 32
    int r  = idx >> 5;
    int s  = r & (SS - 1);
    int bh = r >> 11;           // b*KVH + h  (0..31)
    int b  = bh >> 3;

    float w0 = strat[b * 2 + 0];
    float wl = strat[b * 2 + 1];
    int i = inv[s];
    bool hasLeft = d4 < (RANK / 4);   // d < 64

    float4 kd, vd, kl, vl;
    kl.x = kl.y = kl.z = kl.w = 0.f;
    vl.x = vl.y = vl.z = vl.w = 0.f;
    if (i >= 0) {
        size_t base = ((size_t)bh * SS + i) * DD;
        kd = *((const float4*)(key + base) + d4);
        vd = *((const float4*)(value + base) + d4);
        if (hasLeft) { kl = kd; vl = vd; }
    } else {
        size_t cbase = ((size_t)bh * MAXSEQ + s) * DD;
        kd = *((const float4*)(k_cache + cbase) + d4);
        vd = *((const float4*)(v_cache + cbase) + d4);
        if (hasLeft) {
            size_t lbase = ((size_t)bh * MAXSEQ + s) * RANK;
            kl = *((const float4*)(k_left + lbase) + d4);
            vl = *((const float4*)(v_left + lbase) + d4);
        }
    }
    float4 ko, vo;
    ko.x = fmaf(w0, kd.x, wl * kl.x);
    ko.y = fmaf(w0, kd.y, wl * kl.y);
    ko.z = fmaf(w0, kd.z, wl * kl.z);
    ko.w = fmaf(w0, kd.w, wl * kl.w);
    vo.x = fmaf(w0, vd.x, wl * vl.x);
    vo.y = fmaf(w0, vd.y, wl * vl.y);
    vo.z = fmaf(w0, vd.z, wl * vl.z);
    vo.w = fmaf(w0, vd.w, wl * vl.w);

    float4* outv = (float4*)out;
    const int KV_OFF = BB * KVH * SS * (DD / 4);   // 4,194,304
    outv[idx] = ko;
    outv[idx + KV_OFF] = vo;
}

extern "C" void kernel_launch(void* const* d_in, const int* in_sizes, int n_in,
                              void* d_out, int out_size, void* d_ws, size_t ws_size,
                              hipStream_t stream) {
    const float* hidden   = (const float*)d_in[0];
    const float* key      = (const float*)d_in[1];
    const float* value    = (const float*)d_in[2];
    const float* k_cache  = (const float*)d_in[3];
    const float* v_cache  = (const float*)d_in[4];
    const float* k_left   = (const float*)d_in[5];
    const float* v_left   = (const float*)d_in[6];
    const float* w1       = (const float*)d_in[7];
    const float* b1       = (const float*)d_in[8];
    const float* w2       = (const float*)d_in[9];
    const float* b2       = (const float*)d_in[10];
    const int*   cachepos = (const int*)d_in[11];
    const int*   layeridx = (const int*)d_in[12];
    float* out = (float*)d_out;

    float* wsf = (float*)d_ws;
    int*   inv = (int*)(wsf + WS_FLOATS);
    float* pooled = wsf + WS_POOLED;
    float* hdn    = wsf + WS_HDN;
    float* strat  = wsf + WS_STRAT;

    // 1. init workspace (zeros + inv = -1)
    {
        int n = WS_FLOATS + SS;
        init_ws_kernel<<<(n + 255) / 256, 256, 0, stream>>>(wsf, inv);
    }
    // 2. pooled sums
    pool_kernel<<<BB * (SS / 64) * (HH / 256), 256, 0, stream>>>(hidden, pooled);
    // 3. feats @ w1
    mlp1_kernel<<<(HDN / 256) * 33, 256, 0, stream>>>(wsf, w1, layeridx, hdn);
    // 4. relu -> @w2 -> softmax -> strat
    mlp2_kernel<<<1, 256, 0, stream>>>(hdn, b1, w2, b2, strat);
    // 5. inverse scatter map
    scatter_inv_kernel<<<(SS + 255) / 256, 256, 0, stream>>>(cachepos, inv);
    // 6. fused output
    out_kernel<<<(BB * KVH * SS * (DD / 4)) / 256, 256, 0, stream>>>(
        key, value, k_cache, v_cache, k_left, v_left, strat, inv, out);
}

// Round 2
// 109.042 us; speedup vs baseline: 1.2789x; 1.2789x over previous
//
#include <hip/hip_runtime.h>

// Problem constants (fixed by setup_inputs)
#define BB 4
#define SS 2048
#define HH 4096
#define KVH 8
#define DD 128
#define MAXSEQ 4096
#define RANK 64
#define HDN 1024   // H/4
#define W1ROWS (HH + 2)

// Workspace layout (floats):
//   [0, 16384)      pooled sums  (B*H)
//   [16384, 20480)  hdn          (B*HDN)
//   [20480, 20488)  strat        (B*2)
//   ints at float offset 20488: inv[SS]
#define WS_POOLED 0
#define WS_HDN    16384
#define WS_STRAT  20480
#define WS_FLOATS 20488

__global__ void init_ws_kernel(float* __restrict__ wsf, int* __restrict__ inv) {
    int idx = blockIdx.x * 256 + threadIdx.x;
    if (idx < WS_STRAT) wsf[idx] = 0.0f;       // pooled + hdn
    int j = idx - WS_STRAT;
    if (j >= 0 && j < SS) inv[j] = -1;
}

// Fused: pooled partial sums (float4, atomics) + scatter-inverse map.
// grid = B * 64 * 4 = 1024 blocks, 256 threads.
// Each block: batch b, s-chunk of 32 rows, c-chunk of 1024 channels.
__global__ void pool_scatter_kernel(const float* __restrict__ hidden,
                                    const int* __restrict__ cache_position,
                                    float* __restrict__ pooled,
                                    int* __restrict__ inv) {
    // scatter: first 8 blocks also build inv (init_ws ran in a prior kernel)
    if (blockIdx.x < (SS / 256)) {
        int i = blockIdx.x * 256 + threadIdx.x;
        int pos = cache_position[i];
        if (pos >= 0 && pos < SS) atomicMax(&inv[pos], i);  // last-wins
    }
    int blk = blockIdx.x;
    int cblk = blk & 3;  blk >>= 2;
    int sch  = blk & 63; blk >>= 6;
    int b = blk;
    int c0 = cblk * 1024 + threadIdx.x * 4;
    const float* base = hidden + (size_t)b * SS * HH + (size_t)sch * 32 * HH + c0;
    float4 acc = make_float4(0.f, 0.f, 0.f, 0.f);
    #pragma unroll 8
    for (int s = 0; s < 32; ++s) {
        float4 v = *(const float4*)(base + (size_t)s * HH);
        acc.x += v.x; acc.y += v.y; acc.z += v.z; acc.w += v.w;
    }
    float* p = pooled + b * HH + c0;
    atomicAdd(p + 0, acc.x);
    atomicAdd(p + 1, acc.y);
    atomicAdd(p + 2, acc.z);
    atomicAdd(p + 3, acc.w);
}

// hdn[b][j] += sum_k feats[b][k] * w1[k][j] over a 16-row k-chunk.
// grid = 257 blocks (256*16 = 4096 rows + 1 block for rows 4096,4097).
// 256 threads, each owns 4 consecutive j (float4 over the w1 row).
__global__ void mlp1_kernel(const float* __restrict__ pooled,
                            const float* __restrict__ w1,
                            const int* __restrict__ layer_idx,
                            float* __restrict__ hdn) {
    int kc = blockIdx.x;
    int j0 = threadIdx.x * 4;
    const float inv_s = 1.0f / (float)SS;
    int k0 = kc * 16;
    int kend = min(k0 + 16, W1ROWS);
    float4 acc[BB];
    #pragma unroll
    for (int b = 0; b < BB; ++b) acc[b] = make_float4(0.f, 0.f, 0.f, 0.f);
    for (int k = k0; k < kend; ++k) {
        float4 w = *(const float4*)(w1 + (size_t)k * HDN + j0);
        float f[BB];
        if (k < HH) {
            #pragma unroll
            for (int b = 0; b < BB; ++b) f[b] = pooled[b * HH + k] * inv_s;
        } else if (k == HH) {
            float li = (float)(*layer_idx);
            #pragma unroll
            for (int b = 0; b < BB; ++b) f[b] = li;
        } else {
            #pragma unroll
            for (int b = 0; b < BB; ++b) f[b] = (float)SS;
        }
        #pragma unroll
        for (int b = 0; b < BB; ++b) {
            acc[b].x = fmaf(f[b], w.x, acc[b].x);
            acc[b].y = fmaf(f[b], w.y, acc[b].y);
            acc[b].z = fmaf(f[b], w.z, acc[b].z);
            acc[b].w = fmaf(f[b], w.w, acc[b].w);
        }
    }
    #pragma unroll
    for (int b = 0; b < BB; ++b) {
        float* h = hdn + b * HDN + j0;
        atomicAdd(h + 0, acc[b].x);
        atomicAdd(h + 1, acc[b].y);
        atomicAdd(h + 2, acc[b].z);
        atomicAdd(h + 3, acc[b].w);
    }
}

// One block, 1024 threads (16 waves). Each thread owns one j.
// logits[b][m] = sum_j relu(hdn[b][j]+b1[j]) * w2[j][m]; softmax; strat.
__global__ void mlp2_kernel(const float* __restrict__ hdn,
                            const float* __restrict__ b1,
                            const float* __restrict__ w2,
                            const float* __restrict__ b2,
                            float* __restrict__ strat) {
    __shared__ float wred[16][16];   // [wave][b*4+m]
    __shared__ float logits[16];
    int t = threadIdx.x;
    int wave = t >> 6;
    int lane = t & 63;

    float bias = b1[t];
    float4 w2v = *(const float4*)(w2 + t * 4);
    float l[BB][4];
    #pragma unroll
    for (int b = 0; b < BB; ++b) {
        float h = hdn[b * HDN + t] + bias;
        h = h > 0.f ? h : 0.f;
        l[b][0] = h * w2v.x;
        l[b][1] = h * w2v.y;
        l[b][2] = h * w2v.z;
        l[b][3] = h * w2v.w;
    }
    #pragma unroll
    for (int off = 32; off > 0; off >>= 1) {
        #pragma unroll
        for (int b = 0; b < BB; ++b)
            #pragma unroll
            for (int m = 0; m < 4; ++m)
                l[b][m] += __shfl_down(l[b][m], off, 64);
    }
    if (lane == 0) {
        #pragma unroll
        for (int b = 0; b < BB; ++b)
            #pragma unroll
            for (int m = 0; m < 4; ++m)
                wred[wave][b * 4 + m] = l[b][m];
    }
    __syncthreads();
    if (t < 16) {
        float s = 0.f;
        #pragma unroll
        for (int w = 0; w < 16; ++w) s += wred[w][t];
        logits[t] = s + b2[t & 3];
    }
    __syncthreads();
    if (t < BB) {
        float l0 = logits[t * 4 + 0], l1 = logits[t * 4 + 1];
        float l2 = logits[t * 4 + 2], l3 = logits[t * 4 + 3];
        float mx = fmaxf(fmaxf(l0, l1), fmaxf(l2, l3));
        float e0 = __expf(l0 - mx), e1 = __expf(l1 - mx);
        float e2 = __expf(l2 - mx), e3 = __expf(l3 - mx);
        float denom = e0 + e1 + e2 + e3;
        strat[t * 2 + 0] = e0 / denom;
        strat[t * 2 + 1] = e1 / denom;
    }
}

// One thread per float4 of (b,h,s,d): computes BOTH k_out and v_out.
__global__ void out_kernel(const float* __restrict__ key,
                           const float* __restrict__ value,
                           const float* __restrict__ k_cache,
                           const float* __restrict__ v_cache,
                           const float* __restrict__ k_left,
                           const float* __restrict__ v_left,
                           const float* __restrict__ strat,
                           const int* __restrict__ inv,
                           float* __restrict__ out) {
    int idx = blockIdx.x * 256 + threadIdx.x;   // < 4,194,304
    int d4 = idx & 31;          // D/4 = 32
    int r  = idx >> 5;
    int s  = r & (SS - 1);
    int bh = r >> 11;           // b*KVH + h
    int b  = bh >> 3;

    float w0 = strat[b * 2 + 0];
    float wl = strat[b * 2 + 1];
    int i = inv[s];
    bool hasLeft = d4 < (RANK / 4);   // d < 64

    float4 kd, vd, kl, vl;
    kl.x = kl.y = kl.z = kl.w = 0.f;
    vl.x = vl.y = vl.z = vl.w = 0.f;
    if (i >= 0) {
        size_t base = ((size_t)bh * SS + i) * DD;
        kd = *((const float4*)(key + base) + d4);
        vd = *((const float4*)(value + base) + d4);
        if (hasLeft) { kl = kd; vl = vd; }
    } else {
        size_t cbase = ((size_t)bh * MAXSEQ + s) * DD;
        kd = *((const float4*)(k_cache + cbase) + d4);
        vd = *((const float4*)(v_cache + cbase) + d4);
        if (hasLeft) {
            size_t lbase = ((size_t)bh * MAXSEQ + s) * RANK;
            kl = *((const float4*)(k_left + lbase) + d4);
            vl = *((const float4*)(v_left + lbase) + d4);
        }
    }
    float4 ko, vo;
    ko.x = fmaf(w0, kd.x, wl * kl.x);
    ko.y = fmaf(w0, kd.y, wl * kl.y);
    ko.z = fmaf(w0, kd.z, wl * kl.z);
    ko.w = fmaf(w0, kd.w, wl * kl.w);
    vo.x = fmaf(w0, vd.x, wl * vl.x);
    vo.y = fmaf(w0, vd.y, wl * vl.y);
    vo.z = fmaf(w0, vd.z, wl * vl.z);
    vo.w = fmaf(w0, vd.w, wl * vl.w);

    float4* outv = (float4*)out;
    const int KV_OFF = BB * KVH * SS * (DD / 4);   // 4,194,304
    outv[idx] = ko;
    outv[idx + KV_OFF] = vo;
}

extern "C" void kernel_launch(void* const* d_in, const int* in_sizes, int n_in,
                              void* d_out, int out_size, void* d_ws, size_t ws_size,
                              hipStream_t stream) {
    const float* hidden   = (const float*)d_in[0];
    const float* key      = (const float*)d_in[1];
    const float* value    = (const float*)d_in[2];
    const float* k_cache  = (const float*)d_in[3];
    const float* v_cache  = (const float*)d_in[4];
    const float* k_left   = (const float*)d_in[5];
    const float* v_left   = (const float*)d_in[6];
    const float* w1       = (const float*)d_in[7];
    const float* b1       = (const float*)d_in[8];
    const float* w2       = (const float*)d_in[9];
    const float* b2       = (const float*)d_in[10];
    const int*   cachepos = (const int*)d_in[11];
    const int*   layeridx = (const int*)d_in[12];
    float* out = (float*)d_out;

    float* wsf = (float*)d_ws;
    int*   inv = (int*)(wsf + WS_FLOATS);
    float* pooled = wsf + WS_POOLED;
    float* hdn    = wsf + WS_HDN;
    float* strat  = wsf + WS_STRAT;

    // 1. init workspace (pooled/hdn zeros, inv = -1)
    init_ws_kernel<<<(WS_STRAT + SS + 255) / 256, 256, 0, stream>>>(wsf, inv);
    // 2. pooled partial sums (float4) + inverse scatter map
    pool_scatter_kernel<<<BB * 64 * 4, 256, 0, stream>>>(hidden, cachepos, pooled, inv);
    // 3. feats @ w1 (float4 rows, 257 k-chunks)
    mlp1_kernel<<<257, 256, 0, stream>>>(pooled, w1, layeridx, hdn);
    // 4. relu -> @w2 -> softmax -> strat (one 1024-thread block)
    mlp2_kernel<<<1, 1024, 0, stream>>>(hdn, b1, w2, b2, strat);
    // 5. fused output
    out_kernel<<<(BB * KVH * SS * (DD / 4)) / 256, 256, 0, stream>>>(
        key, value, k_cache, v_cache, k_left, v_left, strat, inv, out);
}